// Round 2
// baseline (581.969 us; speedup 1.0000x reference)
//
#include <hip/hip_runtime.h>
#include <hip/hip_bf16.h>
#include <cstdint>
#include <cstddef>
#include <math.h>

#define NEG_SLOPE 0.2f

__device__ __forceinline__ float lrelu(float x) { return x > 0.f ? x : NEG_SLOPE * x; }

// ---------------- GEMM: xw[N][128] = x[N][128] @ W1[128][128]^T ----------------
__global__ __launch_bounds__(256) void k_gemm1(const float* __restrict__ x,
                                               const float* __restrict__ W1,
                                               float* __restrict__ xw, int N)
{
    __shared__ float As[64][33];    // padded +1: conflict-free column reads
    __shared__ float Bs[128][33];   // Bs[c][kk] = W1[c][k0+kk]
    const int tid = threadIdx.x;
    const int tx = tid & 31, ty = tid >> 5;
    const int bm = blockIdx.x * 64;
    float acc[8][4];
    #pragma unroll
    for (int i = 0; i < 8; i++)
        #pragma unroll
        for (int j = 0; j < 4; j++) acc[i][j] = 0.f;

    for (int k0 = 0; k0 < 128; k0 += 32) {
        // A tile: 64 rows x 32 k (512 float4s)
        #pragma unroll
        for (int t = tid; t < 512; t += 256) {
            int r = t >> 3, q = t & 7;
            int n = bm + r;
            float4 f = make_float4(0.f, 0.f, 0.f, 0.f);
            if (n < N) f = *(const float4*)(x + (size_t)n * 128 + k0 + 4 * q);
            As[r][4*q+0] = f.x; As[r][4*q+1] = f.y; As[r][4*q+2] = f.z; As[r][4*q+3] = f.w;
        }
        // B tile: 128 rows x 32 k (1024 float4s)
        #pragma unroll
        for (int t = tid; t < 1024; t += 256) {
            int c = t >> 3, q = t & 7;
            float4 f = *(const float4*)(W1 + (size_t)c * 128 + k0 + 4 * q);
            Bs[c][4*q+0] = f.x; Bs[c][4*q+1] = f.y; Bs[c][4*q+2] = f.z; Bs[c][4*q+3] = f.w;
        }
        __syncthreads();
        #pragma unroll 4
        for (int kk = 0; kk < 32; kk++) {
            float a[8], b[4];
            #pragma unroll
            for (int i = 0; i < 8; i++) a[i] = As[ty * 8 + i][kk];
            #pragma unroll
            for (int j = 0; j < 4; j++) b[j] = Bs[tx + 32 * j][kk];
            #pragma unroll
            for (int i = 0; i < 8; i++)
                #pragma unroll
                for (int j = 0; j < 4; j++) acc[i][j] = fmaf(a[i], b[j], acc[i][j]);
        }
        __syncthreads();
    }
    #pragma unroll
    for (int i = 0; i < 8; i++) {
        int n = bm + ty * 8 + i;
        if (n < N) {
            #pragma unroll
            for (int j = 0; j < 4; j++)
                xw[(size_t)n * 128 + tx + 32 * j] = acc[i][j];
        }
    }
}

// ---------------- per-node attention logits a_src/a_dst [N][4] ----------------
__global__ __launch_bounds__(256) void k_att1(const float* __restrict__ xw,
                                              const float* __restrict__ att_src,
                                              const float* __restrict__ att_dst,
                                              float* __restrict__ a_src,
                                              float* __restrict__ a_dst, int N)
{
    int wave = (blockIdx.x * blockDim.x + threadIdx.x) >> 6;
    int lane = threadIdx.x & 63;
    if (wave >= N) return;
    float v0 = xw[(size_t)wave * 128 + lane];
    float v1 = xw[(size_t)wave * 128 + 64 + lane];
    float s0 = v0 * att_src[lane], s1 = v1 * att_src[64 + lane];
    float d0 = v0 * att_dst[lane], d1 = v1 * att_dst[64 + lane];
    #pragma unroll
    for (int off = 16; off; off >>= 1) {   // reduce within 32-lane halves (head segments)
        s0 += __shfl_xor(s0, off); s1 += __shfl_xor(s1, off);
        d0 += __shfl_xor(d0, off); d1 += __shfl_xor(d1, off);
    }
    if ((lane & 31) == 0) {
        int h = lane >> 5;                 // 0 or 1
        a_src[wave * 4 + h]     = s0;      // heads 0/1
        a_src[wave * 4 + 2 + h] = s1;      // heads 2/3
        a_dst[wave * 4 + h]     = d0;
        a_dst[wave * 4 + 2 + h] = d1;
    }
}

// ---------------- CSR build (group edges by dst) ----------------
// NOTE: harness passes integer inputs as int32 — edge_index is const int*, NOT int64.
__global__ void k_count(const int* __restrict__ ei, int E, int N, int* __restrict__ deg)
{
    int e = blockIdx.x * blockDim.x + threadIdx.x;
    if (e >= E + N) return;
    int d = (e < E) ? ei[(size_t)E + e] : (e - E);  // self loop for e>=E
    atomicAdd(&deg[d], 1);
}

__global__ __launch_bounds__(1024) void k_scan(const int* __restrict__ deg,
                                               int* __restrict__ row_ptr,
                                               int* __restrict__ cursor, int N)
{
    __shared__ int sums[1024];
    __shared__ int s_carry;
    const int tid = threadIdx.x;
    if (tid == 0) s_carry = 0;
    __syncthreads();
    for (int base = 0; base < N; base += 4096) {
        int idx = base + tid * 4;
        int v[4];
        #pragma unroll
        for (int u = 0; u < 4; u++) v[u] = (idx + u < N) ? deg[idx + u] : 0;
        int tsum = v[0] + v[1] + v[2] + v[3];
        sums[tid] = tsum;
        __syncthreads();
        for (int off = 1; off < 1024; off <<= 1) {
            int t = (tid >= off) ? sums[tid - off] : 0;
            __syncthreads();
            sums[tid] += t;
            __syncthreads();
        }
        int carry = s_carry;
        int excl = carry + sums[tid] - tsum;
        #pragma unroll
        for (int u = 0; u < 4; u++) {
            if (idx + u < N) { row_ptr[idx + u] = excl; cursor[idx + u] = excl; excl += v[u]; }
        }
        __syncthreads();
        if (tid == 0) s_carry = carry + sums[1023];
        __syncthreads();
    }
    if (tid == 0) row_ptr[N] = s_carry;
}

__global__ void k_scatter(const int* __restrict__ ei, int E, int N,
                          int* __restrict__ cursor, int* __restrict__ csr_src)
{
    int e = blockIdx.x * blockDim.x + threadIdx.x;
    if (e >= E + N) return;
    int s, d;
    if (e < E) { s = ei[e]; d = ei[(size_t)E + e]; }
    else       { s = d = e - E; }
    int pos = atomicAdd(&cursor[d], 1);
    csr_src[pos] = s;
}

// ---------------- layer 1: online-softmax aggregation, fused with relu+b1 and h@W2 ----
__global__ __launch_bounds__(256) void k_layer1(const float* __restrict__ xw,
                                                const float* __restrict__ a_src,
                                                const float* __restrict__ a_dst,
                                                const int* __restrict__ row_ptr,
                                                const int* __restrict__ csr_src,
                                                const float* __restrict__ b1,
                                                const float* __restrict__ W2,
                                                float* __restrict__ xw2, int N)
{
    int d = (blockIdx.x * blockDim.x + threadIdx.x) >> 6;   // one wave per dst node
    int lane = threadIdx.x & 63;
    if (d >= N) return;
    float4 ad4 = *(const float4*)(a_dst + (size_t)d * 4);
    int hsel = lane >> 5;                                   // 0/1 -> my heads: hsel, hsel+2
    float adh0 = hsel ? ad4.y : ad4.x;
    float adh1 = hsel ? ad4.w : ad4.z;
    float m0 = -INFINITY, m1 = -INFINITY;
    float l0 = 0.f, l1 = 0.f, acc0 = 0.f, acc1 = 0.f;
    int beg = row_ptr[d], end = row_ptr[d + 1];
    for (int j = beg; j < end; j++) {
        int s = csr_src[j];
        float4 as4 = *(const float4*)(a_src + (size_t)s * 4);
        float al0 = lrelu((hsel ? as4.y : as4.x) + adh0);
        float al1 = lrelu((hsel ? as4.w : as4.z) + adh1);
        float x0 = xw[(size_t)s * 128 + lane];
        float x1 = xw[(size_t)s * 128 + 64 + lane];
        float nm0 = fmaxf(m0, al0);
        float nm1 = fmaxf(m1, al1);
        float sc0 = __expf(m0 - nm0);   // first iter: exp(-inf) = 0
        float sc1 = __expf(m1 - nm1);
        float p0 = __expf(al0 - nm0);
        float p1 = __expf(al1 - nm1);
        l0 = l0 * sc0 + p0;
        l1 = l1 * sc1 + p1;
        acc0 = acc0 * sc0 + p0 * x0;
        acc1 = acc1 * sc1 + p1 * x1;
        m0 = nm0; m1 = nm1;
    }
    float o0 = acc0 / (l0 + 1e-16f) + b1[lane];
    float o1 = acc1 / (l1 + 1e-16f) + b1[64 + lane];
    o0 = fmaxf(o0, 0.f);                                    // relu between layers
    o1 = fmaxf(o1, 0.f);
    // layer-2 projection: xw2[d] = sum_c relu_out[c] * W2[c]  (h never materialized)
    float p = o0 * W2[lane] + o1 * W2[64 + lane];
    #pragma unroll
    for (int off = 32; off; off >>= 1) p += __shfl_xor(p, off);
    if (lane == 0) xw2[d] = p;
}

// ---------------- layer 2: scalar GAT head, lanes parallel over edges ----------------
__global__ __launch_bounds__(256) void k_layer2(const float* __restrict__ xw2,
                                                const int* __restrict__ row_ptr,
                                                const int* __restrict__ csr_src,
                                                const float* __restrict__ att_src2,
                                                const float* __restrict__ att_dst2,
                                                const float* __restrict__ b2,
                                                float* __restrict__ out, int N)
{
    int d = (blockIdx.x * blockDim.x + threadIdx.x) >> 6;
    int lane = threadIdx.x & 63;
    if (d >= N) return;
    float as2 = att_src2[0];
    float adst = xw2[d] * att_dst2[0];
    float m = -INFINITY, l = 0.f, acc = 0.f;
    int beg = row_ptr[d], end = row_ptr[d + 1];
    for (int j = beg + lane; j < end; j += 64) {
        int s = csr_src[j];
        float xs = xw2[s];
        float al = lrelu(xs * as2 + adst);
        float nm = fmaxf(m, al);
        float sc = __expf(m - nm);
        float p = __expf(al - nm);
        l = l * sc + p;
        acc = acc * sc + p * xs;
        m = nm;
    }
    // merge per-lane online-softmax states (guard empty lanes: l==0)
    #pragma unroll
    for (int off = 32; off; off >>= 1) {
        float mo = __shfl_xor(m, off);
        float lo = __shfl_xor(l, off);
        float ao = __shfl_xor(acc, off);
        float nm = fmaxf(m, mo);
        float sa = (l  > 0.f) ? __expf(m  - nm) : 0.f;
        float sb = (lo > 0.f) ? __expf(mo - nm) : 0.f;
        l = l * sa + lo * sb;
        acc = acc * sa + ao * sb;
        m = nm;
    }
    if (lane == 0) out[d] = acc / (l + 1e-16f) + b2[0];
}

extern "C" void kernel_launch(void* const* d_in, const int* in_sizes, int n_in,
                              void* d_out, int out_size, void* d_ws, size_t ws_size,
                              hipStream_t stream)
{
    const float* x        = (const float*)d_in[0];
    const int*   ei       = (const int*)d_in[1];     // int32 per harness convention
    const float* W1       = (const float*)d_in[2];
    const float* att_src1 = (const float*)d_in[3];
    const float* att_dst1 = (const float*)d_in[4];
    const float* b1       = (const float*)d_in[5];
    const float* W2       = (const float*)d_in[6];
    const float* att_src2 = (const float*)d_in[7];
    const float* att_dst2 = (const float*)d_in[8];
    const float* b2       = (const float*)d_in[9];
    float* out = (float*)d_out;

    const int N  = in_sizes[0] / 128;
    const int E  = in_sizes[1] / 2;
    const int Et = E + N;

    char* p = (char*)d_ws;
    auto alloc = [&](size_t bytes) {
        char* r = p;
        p += (bytes + 255) & ~(size_t)255;
        return (void*)r;
    };
    float* xw      = (float*)alloc((size_t)N * 128 * 4);
    float* a_src   = (float*)alloc((size_t)N * 4 * 4);
    float* a_dst   = (float*)alloc((size_t)N * 4 * 4);
    float* xw2     = (float*)alloc((size_t)N * 4);
    int*   deg     = (int*)alloc((size_t)N * 4);
    int*   row_ptr = (int*)alloc((size_t)(N + 1) * 4);
    int*   cursor  = (int*)alloc((size_t)N * 4);
    int*   csr_src = (int*)alloc((size_t)Et * 4);

    hipMemsetAsync(deg, 0, (size_t)N * 4, stream);

    k_gemm1  <<<(N + 63) / 64,    256,  0, stream>>>(x, W1, xw, N);
    k_att1   <<<(N + 3) / 4,      256,  0, stream>>>(xw, att_src1, att_dst1, a_src, a_dst, N);
    k_count  <<<(Et + 255) / 256, 256,  0, stream>>>(ei, E, N, deg);
    k_scan   <<<1,                1024, 0, stream>>>(deg, row_ptr, cursor, N);
    k_scatter<<<(Et + 255) / 256, 256,  0, stream>>>(ei, E, N, cursor, csr_src);
    k_layer1 <<<(N + 3) / 4,      256,  0, stream>>>(xw, a_src, a_dst, row_ptr, csr_src,
                                                     b1, W2, xw2, N);
    k_layer2 <<<(N + 3) / 4,      256,  0, stream>>>(xw2, row_ptr, csr_src, att_src2,
                                                     att_dst2, b2, out, N);
}